// Round 13
// baseline (313.921 us; speedup 1.0000x reference)
//
#include <hip/hip_runtime.h>

// MHA forward, B=2, S=2048, D=1024, H=16, Dk=64, causal, RoPE. fp32 I/O.
// Internal bf16 MFMA 16x16x32, fp32 accum.
// History: R20 WIN qkv 256x192 dbuf 2-phase (228->217); R23 WIN counted
// vmcnt both GEMMs (218->214). attn wave/block restructures all FALSIFIED
// (R12/13/17/18/21); instruction-mix rewrites all NEUTRAL (R14/15/19).
// R24: the untried attn axis is ITERATION GRANULARITY. KVBLK 64->128:
// halves iteration count (25->12.5 avg) and thus the per-iter fixed cost
// (barrier wait, V-stage sync, K-load latency) that six neutral rewrites
// proved is not instruction-bound. Kept invariants: equal-work pairs
// (procs = (qtA>>1)+(qtB>>1)+2 = 17 for all pairs), 256 thr, one
// barrier/iter, swapped-QK + sigma-PV. Diag mask: j==qt>>1 with
// qrel = ((qt&1)<<6)+wave*16+l16. K loads: kc dead after QK -> next-tile
// loads issue post-QK into the same regs (zero extra VGPR, ~1000cy cover).
// LDS 18.4->34.8KB (VSTR=136 keeps 2-way banks). +6% FLOPs (half-masked
// diag tile per pair). No forced launch bounds (R12/R17 law).

typedef unsigned short u16;
typedef __attribute__((ext_vector_type(8))) short short8;   // 8 bf16 = 4 VGPRs
typedef __attribute__((ext_vector_type(4))) float float4v;  // MFMA C/D

typedef const __attribute__((address_space(1))) void GV;    // global
typedef __attribute__((address_space(3))) void LV;          // LDS

#define VSTR 136  // attn Vt row stride (u16) for 128 KV cols: 272B rows, 2-way banks
#define QSCL 0.18033688011112042f   // 0.125 * log2(e)

__device__ __forceinline__ u16 f2b(float f) {
    union { float f; unsigned int i; } t; t.f = f;
    unsigned int r = t.i + 0x7fffu + ((t.i >> 16) & 1u);   // RNE
    return (u16)(r >> 16);
}

// ---------------- fused fp32 -> bf16 converter + RoPE table -----------------
// blocks 0..4095: cvt x/wq/wk/wv/wo. blocks 4096..4351: tab[pos*32+fi].
__global__ __launch_bounds__(256) void cvt_all(
    const float4* __restrict__ x,  const float4* __restrict__ wq,
    const float4* __restrict__ wk, const float4* __restrict__ wv,
    const float4* __restrict__ wo,
    u16* __restrict__ xb, u16* __restrict__ wcat, u16* __restrict__ wob,
    float2* __restrict__ tab)
{
    const int blk = blockIdx.x;
    if (blk >= 4096) {                 // RoPE cos/sin table
        const int i = (blk - 4096) * 256 + threadIdx.x;   // 0..65535
        const int pos = i >> 5, fi = i & 31;
        const float freq = exp2f((float)fi * -0.4152410118609203f);  // -log2(1e4)/32
        float sn, cs; sincosf((float)pos * freq, &sn, &cs);
        tab[i] = make_float2(cs, sn);
        return;
    }
    const int i = blk * 256 + threadIdx.x;
    const float4* s; u16* d; int off;
    if (i < 524288) { s = x; d = xb; off = i; }
    else {
        const int widx = i - 524288;
        const int w = widx >> 17, o = widx & 131071;
        switch (w) {
            case 0:  s = wq; d = wcat;              break;
            case 1:  s = wk; d = wcat + (1 << 20);  break;
            case 2:  s = wv; d = wcat + (2 << 20);  break;
            default: s = wo; d = wob;               break;
        }
        off = o;
    }
    float4 a = s[2 * off], b = s[2 * off + 1];
    u16 t[8] = {f2b(a.x), f2b(a.y), f2b(a.z), f2b(a.w),
                f2b(b.x), f2b(b.y), f2b(b.z), f2b(b.w)};
    reinterpret_cast<int4*>(d)[off] = *reinterpret_cast<int4*>(t);
}

// ---------------------------------------------------------------------------
// QKV GEMM: 256(m) x 192(n) x 64(k) steps, 512 threads, 8 waves (2m x 4n),
// double-buffered LDS (112KB). R23 counted-vmcnt schedule. Grid 256 = 1
// block/CU. RoPE epilogue.
// ---------------------------------------------------------------------------
__global__ __launch_bounds__(512) void gemm_qkv(
    const u16* __restrict__ X, const u16* __restrict__ Wb,
    u16* __restrict__ Yq, u16* __restrict__ Yk, u16* __restrict__ Yv,
    const float2* __restrict__ tab)
{
    __shared__ u16 As[2][256 * 64];   // 2 x 32KB
    __shared__ u16 Bs[2][192 * 64];   // 2 x 24KB

    const int tid  = threadIdx.x;
    const int wave = tid >> 6;                          // 0..7
    const int lane = tid & 63;
    const int quad = lane >> 4;
    const int l16  = lane & 15;
    const int wm = (wave >> 2) * 128;                   // 0,128
    const int wn = (wave & 3) * 48;                     // 0,48,96,144
    const int g = blockIdx.x;
    const int rr = g >> 3;                              // 0..31
    const int m0 = ((g & 7) * 2 + (rr >> 4)) * 256;     // 16 m-tiles
    const int n0 = (rr & 15) * 192;                     // 16 n-tiles
    const int lrow = lane >> 3;                         // 0..7 within 8-row slab
    const int cg8  = (lane & 7) ^ lrow;                 // swizzled global unit

    float4v acc[8][3];
#pragma unroll
    for (int mt = 0; mt < 8; mt++)
#pragma unroll
        for (int nt = 0; nt < 3; nt++) acc[mt][nt] = (float4v){0.f, 0.f, 0.f, 0.f};

    auto stage = [&](int bsel, int kb) {                // 7 loads/thread
#pragma unroll
        for (int t = 0; t < 4; t++) {                   // A: 32 slabs of 8 rows
            const int I = wave * 4 + t;
            const u16* gp = X + (size_t)(m0 + I * 8 + lrow) * 1024 + kb + cg8 * 8;
            __builtin_amdgcn_global_load_lds((GV*)gp, (LV*)&As[bsel][I * 512], 16, 0, 0);
        }
#pragma unroll
        for (int t = 0; t < 3; t++) {                   // B: 24 slabs of 8 rows
            const int I = wave * 3 + t;
            const u16* gp = Wb + (size_t)(n0 + I * 8 + lrow) * 1024 + kb + cg8 * 8;
            __builtin_amdgcn_global_load_lds((GV*)gp, (LV*)&Bs[bsel][I * 512], 16, 0, 0);
        }
    };

    stage(0, 0);
    stage(1, 64);                                       // 14 loads in flight

    for (int kbi = 0; kbi < 16; kbi++) {
        const int cur = kbi & 1;
        if (kbi < 15) { asm volatile("s_waitcnt vmcnt(7)" ::: "memory"); }
        else          { asm volatile("s_waitcnt vmcnt(0)" ::: "memory"); }
        __builtin_amdgcn_sched_barrier(0);
        __builtin_amdgcn_s_barrier();                   // all waves: buf[cur] ready
        __builtin_amdgcn_sched_barrier(0);
        __builtin_amdgcn_s_setprio(1);
#pragma unroll
        for (int ks = 0; ks < 2; ks++) {
            const int su = ((ks * 4 + quad) ^ (l16 & 7)) * 8;   // swizzled unit
            short8 af[8], bf[3];
#pragma unroll
            for (int t = 0; t < 8; t++)
                af[t] = *reinterpret_cast<const short8*>(&As[cur][(wm + t * 16 + l16) * 64 + su]);
#pragma unroll
            for (int t = 0; t < 3; t++)
                bf[t] = *reinterpret_cast<const short8*>(&Bs[cur][(wn + t * 16 + l16) * 64 + su]);
#pragma unroll
            for (int mt = 0; mt < 8; mt++)
#pragma unroll
                for (int nt = 0; nt < 3; nt++)
                    acc[mt][nt] = __builtin_amdgcn_mfma_f32_16x16x32_bf16(af[mt], bf[nt], acc[mt][nt], 0, 0, 0);
        }
        __builtin_amdgcn_s_setprio(0);
        __builtin_amdgcn_sched_barrier(0);
        __builtin_amdgcn_s_barrier();                   // all readers done
        __builtin_amdgcn_sched_barrier(0);
        if (kbi < 14) stage(cur, (kbi + 2) * 64);       // refill (overwrite safe)
    }

    // RoPE epilogue
#pragma unroll
    for (int nt = 0; nt < 3; nt++) {
        const int cg = n0 + wn + nt * 16 + l16;      // global col 0..3071
        const int buf = cg >> 10;                    // 0=q 1=k 2=v
        const int c = cg & 1023;
        u16* dst = (buf == 0) ? Yq : ((buf == 1) ? Yk : Yv);
        const bool rp = (buf < 2);
        const float scl = (buf == 0) ? QSCL : 1.0f;
        const int fi = (cg & 63) >> 1;               // pair index in head
#pragma unroll
        for (int mt = 0; mt < 8; mt++)
#pragma unroll
            for (int r = 0; r < 4; r++) {
                const int row = m0 + wm + mt * 16 + quad * 4 + r;
                float v = acc[mt][nt][r];
                if (rp) {
                    const float2 t = tab[((row & 2047) << 5) + fi];
                    const float partner = __shfl_xor(v, 1);
                    v = (l16 & 1) ? fmaf(v, t.x,  partner * t.y)
                                  : fmaf(v, t.x, -partner * t.y);
                }
                dst[(size_t)row * 1024 + c] = f2b(v * scl);
            }
    }
}

// ---------------------------------------------------------------------------
// Out-proj GEMM: 256(m) x 64(n) x 64(k) steps, 512 threads, 8 waves
// (4m x 2n), acc[4][2], dbuf LDS (80KB). R23 counted-vmcnt (L=5).
// Grid 256 = 1 block/CU. f32 output.
// ---------------------------------------------------------------------------
__global__ __launch_bounds__(512) void gemm_proj(
    const u16* __restrict__ X, const u16* __restrict__ Wb,
    float* __restrict__ Yf)
{
    __shared__ u16 As[2][256 * 64];   // 2 x 32KB
    __shared__ u16 Bs[2][64 * 64];    // 2 x 8KB

    const int tid  = threadIdx.x;
    const int wave = tid >> 6;                          // 0..7
    const int lane = tid & 63;
    const int quad = lane >> 4;
    const int l16  = lane & 15;
    const int wm = (wave >> 1) * 64;                    // 0,64,128,192
    const int wn = (wave & 1) * 32;                     // 0,32
    const int g = blockIdx.x;
    const int rr = g >> 3;                              // 0..31
    const int m0 = ((g & 7) * 2 + (rr >> 4)) * 256;     // 16 m-tiles
    const int n0 = (rr & 15) * 64;                      // 16 n-tiles
    const int lrow = lane >> 3;                         // 0..7 within 8-row slab
    const int cg8  = (lane & 7) ^ lrow;                 // swizzled global unit

    float4v acc[4][2];
#pragma unroll
    for (int mt = 0; mt < 4; mt++)
#pragma unroll
        for (int nt = 0; nt < 2; nt++) acc[mt][nt] = (float4v){0.f, 0.f, 0.f, 0.f};

    auto stage = [&](int bsel, int kb) {                // 5 loads/thread
#pragma unroll
        for (int t = 0; t < 4; t++) {                   // A: 32 slabs of 8 rows
            const int I = wave * 4 + t;
            const u16* gp = X + (size_t)(m0 + I * 8 + lrow) * 1024 + kb + cg8 * 8;
            __builtin_amdgcn_global_load_lds((GV*)gp, (LV*)&As[bsel][I * 512], 16, 0, 0);
        }
        {                                               // B: 8 slabs, 1/wave
            const u16* gp = Wb + (size_t)(n0 + wave * 8 + lrow) * 1024 + kb + cg8 * 8;
            __builtin_amdgcn_global_load_lds((GV*)gp, (LV*)&Bs[bsel][wave * 512], 16, 0, 0);
        }
    };

    stage(0, 0);
    stage(1, 64);                                       // 10 loads in flight

    for (int kbi = 0; kbi < 16; kbi++) {
        const int cur = kbi & 1;
        if (kbi < 15) { asm volatile("s_waitcnt vmcnt(5)" ::: "memory"); }
        else          { asm volatile("s_waitcnt vmcnt(0)" ::: "memory"); }
        __builtin_amdgcn_sched_barrier(0);
        __builtin_amdgcn_s_barrier();                   // all waves: buf[cur] ready
        __builtin_amdgcn_sched_barrier(0);
        __builtin_amdgcn_s_setprio(1);
#pragma unroll
        for (int ks = 0; ks < 2; ks++) {
            const int su = ((ks * 4 + quad) ^ (l16 & 7)) * 8;   // swizzled unit
            short8 af[4], bf[2];
#pragma unroll
            for (int t = 0; t < 4; t++)
                af[t] = *reinterpret_cast<const short8*>(&As[cur][(wm + t * 16 + l16) * 64 + su]);
#pragma unroll
            for (int t = 0; t < 2; t++)
                bf[t] = *reinterpret_cast<const short8*>(&Bs[cur][(wn + t * 16 + l16) * 64 + su]);
#pragma unroll
            for (int mt = 0; mt < 4; mt++)
#pragma unroll
                for (int nt = 0; nt < 2; nt++)
                    acc[mt][nt] = __builtin_amdgcn_mfma_f32_16x16x32_bf16(af[mt], bf[nt], acc[mt][nt], 0, 0, 0);
        }
        __builtin_amdgcn_s_setprio(0);
        __builtin_amdgcn_sched_barrier(0);
        __builtin_amdgcn_s_barrier();                   // all readers done
        __builtin_amdgcn_sched_barrier(0);
        if (kbi < 14) stage(cur, (kbi + 2) * 64);       // refill (overwrite safe)
    }

#pragma unroll
    for (int nt = 0; nt < 2; nt++) {
        const int col = n0 + wn + nt * 16 + l16;
#pragma unroll
        for (int mt = 0; mt < 4; mt++)
#pragma unroll
            for (int r = 0; r < 4; r++) {
                const int row = m0 + wm + mt * 16 + quad * 4 + r;
                Yf[(size_t)row * 1024 + col] = acc[mt][nt][r];
            }
    }
}

// ---------------------------------------------------------------------------
// Flash causal attention, KVBLK=128 (R24). Paired q-tiles (qtA, 31-qtA) ->
// 512 equal-work blocks, 256 threads. 17 procs/pair. Iterations j=0..qtB>>1
// (9-16); dual-proc while j<=qtA>>1. Unnormalized softmax (q pre-scaled
// 0.125*log2e, p=exp2f). Swapped QK^T: lane holds S[q=wave*16+l16]
// [k=nt*16+quad*4+r], nt 0..7 (128 k). sigma-PV: pa[ks]=packed own words,
// ks 0..3; vf = 2 x b64 at sigma'd k-offsets. Diag mask: j==qt>>1,
// qrel=((qt&1)<<6)+wave*16+l16. Double-buffered Vt[2][64][136], one
// barrier/iter. kc loaded for tile j+1 right after QK of tile j (kc dead
// there; ~1000cy cover, zero extra VGPR). O aliases Q.
// ---------------------------------------------------------------------------
__global__ __launch_bounds__(256, 2) void attn_kernel(
    const u16* Q, const u16* __restrict__ K,
    const u16* __restrict__ V, u16* O)
{
    __shared__ __align__(16) u16 Vt[2][64 * VSTR];   // [d 0..63][s 0..127 swz]

    const int tid  = threadIdx.x;
    const int wave = tid >> 6;
    const int lane = tid & 63;
    const int quad = lane >> 4;
    const int l16  = lane & 15;
    const int g = blockIdx.x;
    const int xcd = g & 7, slot = g >> 3;
    const int G = (slot >> 4) * 8 + xcd;    // 0..31 = (b,h) group
    const int qtA = slot & 15;              // 0..15
    const int qtB = 31 - qtA;               // 31..16
    const int jAmax = qtA >> 1;             // 0..7
    const int jBmax = qtB >> 1;             // 8..15
    const int b = G & 1, h = G >> 1;
    const size_t base = ((size_t)b * 2048) * 1024 + (size_t)h * 64;

    short8 qfA[2], qfB[2];
    {
        const size_t ra = base + (size_t)(qtA * 64 + wave * 16 + l16) * 1024;
        qfA[0] = *reinterpret_cast<const short8*>(Q + ra + quad * 8);
        qfA[1] = *reinterpret_cast<const short8*>(Q + ra + 32 + quad * 8);
        const size_t rb = base + (size_t)(qtB * 64 + wave * 16 + l16) * 1024;
        qfB[0] = *reinterpret_cast<const short8*>(Q + rb + quad * 8);
        qfB[1] = *reinterpret_cast<const short8*>(Q + rb + 32 + quad * 8);
    }

    float4v oA[4], oB[4];
#pragma unroll
    for (int i = 0; i < 4; i++) { oA[i] = (float4v){0.f,0.f,0.f,0.f}; oB[i] = (float4v){0.f,0.f,0.f,0.f}; }
    float sA = 0.f, sB = 0.f;               // row-sum partial for q = wave*16+l16

    // V staging: thread -> s-row srow2 = tid>>1 (0..127), d-base (tid&1)*32
    const int srow2 = tid >> 1;
    const int dbase = (tid & 1) << 5;
    const u16* Vp = V + base + (size_t)srow2 * 1024 + dbase;
    const u16* kbase = K + base + (size_t)l16 * 1024 + quad * 8;

    int4 vr[4];
#pragma unroll
    for (int t = 0; t < 4; t++)             // V tile 0
        vr[t] = *reinterpret_cast<const int4*>(Vp + t * 8);

    short8 kc[8][2];
    auto loadK = [&](int jn) {              // K tile jn (16 b128/lane)
        const u16* kp = kbase + (size_t)jn * 131072;
#pragma unroll
        for (int nt = 0; nt < 8; nt++)
#pragma unroll
            for (int kd = 0; kd < 2; kd++)
                kc[nt][kd] = *reinterpret_cast<const short8*>(kp + (size_t)(nt * 16) * 1024 + kd * 32);
    };
    loadK(0);

    auto stageV = [&](u16* D) {             // vr -> D, swizzled transpose
#pragma unroll
        for (int t = 0; t < 4; t++) {
            const int d0 = dbase + 8 * t;
            const int sxw = srow2 ^ (((d0 >> 4) & 3) << 4);
            const u16* a = reinterpret_cast<const u16*>(&vr[t]);
#pragma unroll
            for (int e = 0; e < 8; e++) D[(d0 + e) * VSTR + sxw] = a[e];
        }
    };
    stageV(Vt[0]);                          // prologue: tile 0 in Vt[0]
#pragma unroll
    for (int t = 0; t < 4; t++)             // prefetch V tile 1
        vr[t] = *reinterpret_cast<const int4*>(Vp + 131072 + t * 8);

    const int qrelA = ((qtA & 1) << 6) + wave * 16 + l16;
    const int qrelB = ((qtB & 1) << 6) + wave * 16 + l16;

    // SWAPPED QK: sacc[nt][r] = S[q][k = nt*16 + quad*4 + r], k in [0,128)
    auto qk8 = [&](const short8 (&qf)[2], float4v (&sacc)[8]) {
#pragma unroll
        for (int nt = 0; nt < 8; nt++) {
            sacc[nt] = (float4v){0.f, 0.f, 0.f, 0.f};
#pragma unroll
            for (int kd = 0; kd < 2; kd++)
                sacc[nt] = __builtin_amdgcn_mfma_f32_16x16x32_bf16(kc[nt][kd], qf[kd], sacc[nt], 0, 0, 0);
        }
    };
    // softmax + pack; sigma-PV: pa[ks] = (w[2ks][0], w[2ks][1], w[2ks+1][0],
    // w[2ks+1][1]) -- lane-local, zero cross-lane ops.
    auto smx8 = [&](const float4v (&sacc)[8], float &sr, short8 (&pa)[4], bool diag, int qrel) {
        unsigned int w[8][2];
#pragma unroll
        for (int nt = 0; nt < 8; nt++) {
            float p[4];
#pragma unroll
            for (int r = 0; r < 4; r++) {
                float sv = sacc[nt][r];                      // log2-domain
                if (diag && (nt * 16 + quad * 4 + r > qrel)) sv = -1e30f;
                p[r] = exp2f(sv);                            // masked -> 0
                sr += p[r];
            }
            asm("v_cvt_pk_bf16_f32 %0, %1, %2" : "=v"(w[nt][0]) : "v"(p[0]), "v"(p[1]));
            asm("v_cvt_pk_bf16_f32 %0, %1, %2" : "=v"(w[nt][1]) : "v"(p[2]), "v"(p[3]));
        }
#pragma unroll
        for (int ks = 0; ks < 4; ks++) {
            union { unsigned int u[4]; short8 s8; } t;
            t.u[0] = w[2 * ks][0];     t.u[1] = w[2 * ks][1];
            t.u[2] = w[2 * ks + 1][0]; t.u[3] = w[2 * ks + 1][1];
            pa[ks] = t.s8;
        }
    };

    for (int j = 0; j <= jBmax; j++) {
        __syncthreads();   // Vt[(j+1)&1]'s iter-(j-1) readers done; Vt[j&1] writes visible
        if (j < jBmax) stageV(Vt[(j + 1) & 1]);
        if (j + 2 <= jBmax) {
#pragma unroll
            for (int t = 0; t < 4; t++)
                vr[t] = *reinterpret_cast<const int4*>(Vp + (size_t)(j + 2) * 131072 + t * 8);
        }
        const u16* Bt = Vt[j & 1];

        if (j <= jAmax) {  // dual proc (A diag possible; B diag never: jBmax>jAmax)
            float4v xA[8];
            short8 paA[4], paB[4];
            qk8(qfA, xA);
            smx8(xA, sA, paA, j == jAmax, qrelA);
            float4v xB[8];
            qk8(qfB, xB);
            if (j < jBmax) loadK(j + 1);   // kc dead after QK; cover = smx+PV
            smx8(xB, sB, paB, false, qrelB);
#pragma unroll
            for (int ks = 0; ks < 4; ks++) {
                short8 vfk[4];
#pragma unroll
                for (int dt = 0; dt < 4; dt++) {
                    const int rb = (dt * 16 + l16) * VSTR;
                    const int k1 = (ks * 32 + quad * 4) ^ (dt << 4);
                    const int k2 = (ks * 32 + 16 + quad * 4) ^ (dt << 4);
                    union { struct { uint2 lo, hi; } p; short8 s8; } u;
                    u.p.lo = *reinterpret_cast<const uint2*>(&Bt[rb + k1]);
                    u.p.hi = *reinterpret_cast<const uint2*>(&Bt[rb + k2]);
                    vfk[dt] = u.s8;
                }
#pragma unroll
                for (int dt = 0; dt < 4; dt++) {
                    oA[dt] = __builtin_amdgcn_mfma_f32_16x16x32_bf16(paA[ks], vfk[dt], oA[dt], 0, 0, 0);
                    oB[dt] = __builtin_amdgcn_mfma_f32_16x16x32_bf16(paB[ks], vfk[dt], oB[dt], 0, 0, 0);
                }
            }
        } else {           // tail: only B
            float4v xB[8];
            short8 paB[4];
            qk8(qfB, xB);
            if (j < jBmax) loadK(j + 1);
            smx8(xB, sB, paB, j == jBmax, qrelB);
#pragma unroll
            for (int ks = 0; ks < 4; ks++) {
                short8 vfk[4];
#pragma unroll
                for (int dt = 0; dt < 4; dt++) {
                    const int rb = (dt * 16 + l16) * VSTR;
                    const int k1 = (ks * 32 + quad * 4) ^ (dt << 4);
                    const int k2 = (ks * 32 + 16 + quad * 4) ^ (dt << 4);
                    union { struct { uint2 lo, hi; } p; short8 s8; } u;
                    u.p.lo = *reinterpret_cast<const uint2*>(&Bt[rb + k1]);
                    u.p.hi = *reinterpret_cast<const uint2*>(&Bt[rb + k2]);
                    vfk[dt] = u.s8;
                }
#pragma unroll
                for (int dt = 0; dt < 4; dt++)
                    oB[dt] = __builtin_amdgcn_mfma_f32_16x16x32_bf16(paB[ks], vfk[dt], oB[dt], 0, 0, 0);
            }
        }
    }

    // epilogue: quad-reduce row sums, redistribute via shfl, normalize, write
    float tA = sA, tB = sB;
    tA += __shfl_xor(tA, 16); tA += __shfl_xor(tA, 32);
    tB += __shfl_xor(tB, 16); tB += __shfl_xor(tB, 32);
#pragma unroll
    for (int r = 0; r < 4; r++) {
        const int rl = quad * 4 + r;                 // q-local of o[.][r]
        const float invA = 1.0f / __shfl(tA, rl);    // lane rl holds q=wave*16+rl
        const float invB = 1.0f / __shfl(tB, rl);
        const size_t rowA = base + (size_t)(qtA * 64 + wave * 16 + rl) * 1024;
        const size_t rowB = base + (size_t)(qtB * 64 + wave * 16 + rl) * 1024;
#pragma unroll
        for (int dt = 0; dt < 4; dt++) {
            O[rowA + dt * 16 + l16] = f2b(oA[dt][r] * invA);
            O[rowB + dt * 16 + l16] = f2b(oB[dt][r] * invB);
        }
    }
}

// ---------------------------------------------------------------------------
extern "C" void kernel_launch(void* const* d_in, const int* in_sizes, int n_in,
                              void* d_out, int out_size, void* d_ws, size_t ws_size,
                              hipStream_t stream) {
    (void)in_sizes; (void)n_in; (void)out_size; (void)ws_size;
    const float* x  = (const float*)d_in[0];
    const float* wq = (const float*)d_in[1];
    const float* wk = (const float*)d_in[2];
    const float* wv = (const float*)d_in[3];
    const float* wo = (const float*)d_in[4];

    const size_t MN = (size_t)4096 * 1024;

    // d_out (16MB): xb (8MB) + wcat (6MB) + rope table (512KB in free tail);
    // all consumed before the final fp32 GEMM overwrites d_out.
    u16* xb   = (u16*)d_out;
    u16* wcat = xb + MN;                    // [3072][1024] = wq|wk|wv rows
    float2* tab = (float2*)(wcat + (size_t)3072 * 1024);
    u16* qbuf = (u16*)d_ws;                 // also attention output
    u16* kbuf = qbuf + MN;
    u16* vbuf = kbuf + MN;
    u16* wob  = vbuf + MN;                  // ws total: 26MB

    cvt_all<<<4352, 256, 0, stream>>>((const float4*)x, (const float4*)wq,
                                      (const float4*)wk, (const float4*)wv,
                                      (const float4*)wo, xb, wcat, wob, tab);
    gemm_qkv<<<256, 512, 0, stream>>>(xb, wcat, qbuf, kbuf, vbuf, tab);
    attn_kernel<<<512, 256, 0, stream>>>(qbuf, kbuf, vbuf, qbuf);
    gemm_proj<<<256, 512, 0, stream>>>(qbuf, wob, (float*)d_out);
}

// Round 14
// 213.434 us; speedup vs baseline: 1.4708x; 1.4708x over previous
//
#include <hip/hip_runtime.h>

// MHA forward, B=2, S=2048, D=1024, H=16, Dk=64, causal, RoPE. fp32 I/O.
// Internal bf16 MFMA 16x16x32, fp32 accum.
// FINAL FORM (R25 = R23 verbatim revert). Ledger:
//  attn: 6 inner-loop rewrites NEUTRAL (70-72us pinned; 2 waves/SIMD
//  latency floor); 5 restructures FALSIFIED -- R12/13 un-pair (spill /
//  dispatch imbalance), R17/18 8-wave (forced-bound spill / barrier
//  convoy), R21 KV-split atomic merge (+284MB traffic), R24 KVBLK=128
//  (live-set >256 VGPR -> 284MB spill traffic, 184us).
//  GEMMs: R20 WIN 256x192 dbuf 2-phase 1-blk/CU (228->217); R23 WIN
//  counted-vmcnt + raw barriers + setprio (218->214). R22 proj port
//  NEUTRAL. 213.8us best, absmax 0.015625.

typedef unsigned short u16;
typedef __attribute__((ext_vector_type(8))) short short8;   // 8 bf16 = 4 VGPRs
typedef __attribute__((ext_vector_type(4))) float float4v;  // MFMA C/D

typedef const __attribute__((address_space(1))) void GV;    // global
typedef __attribute__((address_space(3))) void LV;          // LDS

#define VSTR 72   // attn Vt row stride (u16): 144B rows, 2-way read banks
#define QSCL 0.18033688011112042f   // 0.125 * log2(e)

__device__ __forceinline__ u16 f2b(float f) {
    union { float f; unsigned int i; } t; t.f = f;
    unsigned int r = t.i + 0x7fffu + ((t.i >> 16) & 1u);   // RNE
    return (u16)(r >> 16);
}

// ---------------- fused fp32 -> bf16 converter + RoPE table -----------------
// blocks 0..4095: cvt x/wq/wk/wv/wo. blocks 4096..4351: tab[pos*32+fi].
__global__ __launch_bounds__(256) void cvt_all(
    const float4* __restrict__ x,  const float4* __restrict__ wq,
    const float4* __restrict__ wk, const float4* __restrict__ wv,
    const float4* __restrict__ wo,
    u16* __restrict__ xb, u16* __restrict__ wcat, u16* __restrict__ wob,
    float2* __restrict__ tab)
{
    const int blk = blockIdx.x;
    if (blk >= 4096) {                 // RoPE cos/sin table
        const int i = (blk - 4096) * 256 + threadIdx.x;   // 0..65535
        const int pos = i >> 5, fi = i & 31;
        const float freq = exp2f((float)fi * -0.4152410118609203f);  // -log2(1e4)/32
        float sn, cs; sincosf((float)pos * freq, &sn, &cs);
        tab[i] = make_float2(cs, sn);
        return;
    }
    const int i = blk * 256 + threadIdx.x;
    const float4* s; u16* d; int off;
    if (i < 524288) { s = x; d = xb; off = i; }
    else {
        const int widx = i - 524288;
        const int w = widx >> 17, o = widx & 131071;
        switch (w) {
            case 0:  s = wq; d = wcat;              break;
            case 1:  s = wk; d = wcat + (1 << 20);  break;
            case 2:  s = wv; d = wcat + (2 << 20);  break;
            default: s = wo; d = wob;               break;
        }
        off = o;
    }
    float4 a = s[2 * off], b = s[2 * off + 1];
    u16 t[8] = {f2b(a.x), f2b(a.y), f2b(a.z), f2b(a.w),
                f2b(b.x), f2b(b.y), f2b(b.z), f2b(b.w)};
    reinterpret_cast<int4*>(d)[off] = *reinterpret_cast<int4*>(t);
}

// ---------------------------------------------------------------------------
// QKV GEMM: 256(m) x 192(n) x 64(k) steps, 512 threads, 8 waves (2m x 4n),
// double-buffered LDS (112KB). Counted-vmcnt schedule -- per K-step:
// vmcnt(7) [oldest 7 = buf cur landed] -> barrier -> MFMA (setprio 1) ->
// barrier -> refill buf cur with K-step kbi+2. No vmcnt(0) drain in loop.
// Grid 256 = 1 block/CU. RoPE epilogue.
// ---------------------------------------------------------------------------
__global__ __launch_bounds__(512) void gemm_qkv(
    const u16* __restrict__ X, const u16* __restrict__ Wb,
    u16* __restrict__ Yq, u16* __restrict__ Yk, u16* __restrict__ Yv,
    const float2* __restrict__ tab)
{
    __shared__ u16 As[2][256 * 64];   // 2 x 32KB
    __shared__ u16 Bs[2][192 * 64];   // 2 x 24KB

    const int tid  = threadIdx.x;
    const int wave = tid >> 6;                          // 0..7
    const int lane = tid & 63;
    const int quad = lane >> 4;
    const int l16  = lane & 15;
    const int wm = (wave >> 2) * 128;                   // 0,128
    const int wn = (wave & 3) * 48;                     // 0,48,96,144
    const int g = blockIdx.x;
    const int rr = g >> 3;                              // 0..31
    const int m0 = ((g & 7) * 2 + (rr >> 4)) * 256;     // 16 m-tiles
    const int n0 = (rr & 15) * 192;                     // 16 n-tiles
    const int lrow = lane >> 3;                         // 0..7 within 8-row slab
    const int cg8  = (lane & 7) ^ lrow;                 // swizzled global unit

    float4v acc[8][3];
#pragma unroll
    for (int mt = 0; mt < 8; mt++)
#pragma unroll
        for (int nt = 0; nt < 3; nt++) acc[mt][nt] = (float4v){0.f, 0.f, 0.f, 0.f};

    auto stage = [&](int bsel, int kb) {                // 7 loads/thread
#pragma unroll
        for (int t = 0; t < 4; t++) {                   // A: 32 slabs of 8 rows
            const int I = wave * 4 + t;
            const u16* gp = X + (size_t)(m0 + I * 8 + lrow) * 1024 + kb + cg8 * 8;
            __builtin_amdgcn_global_load_lds((GV*)gp, (LV*)&As[bsel][I * 512], 16, 0, 0);
        }
#pragma unroll
        for (int t = 0; t < 3; t++) {                   // B: 24 slabs of 8 rows
            const int I = wave * 3 + t;
            const u16* gp = Wb + (size_t)(n0 + I * 8 + lrow) * 1024 + kb + cg8 * 8;
            __builtin_amdgcn_global_load_lds((GV*)gp, (LV*)&Bs[bsel][I * 512], 16, 0, 0);
        }
    };

    stage(0, 0);
    stage(1, 64);                                       // 14 loads in flight

    for (int kbi = 0; kbi < 16; kbi++) {
        const int cur = kbi & 1;
        if (kbi < 15) { asm volatile("s_waitcnt vmcnt(7)" ::: "memory"); }
        else          { asm volatile("s_waitcnt vmcnt(0)" ::: "memory"); }
        __builtin_amdgcn_sched_barrier(0);
        __builtin_amdgcn_s_barrier();                   // all waves: buf[cur] ready
        __builtin_amdgcn_sched_barrier(0);
        __builtin_amdgcn_s_setprio(1);
#pragma unroll
        for (int ks = 0; ks < 2; ks++) {
            const int su = ((ks * 4 + quad) ^ (l16 & 7)) * 8;   // swizzled unit
            short8 af[8], bf[3];
#pragma unroll
            for (int t = 0; t < 8; t++)
                af[t] = *reinterpret_cast<const short8*>(&As[cur][(wm + t * 16 + l16) * 64 + su]);
#pragma unroll
            for (int t = 0; t < 3; t++)
                bf[t] = *reinterpret_cast<const short8*>(&Bs[cur][(wn + t * 16 + l16) * 64 + su]);
#pragma unroll
            for (int mt = 0; mt < 8; mt++)
#pragma unroll
                for (int nt = 0; nt < 3; nt++)
                    acc[mt][nt] = __builtin_amdgcn_mfma_f32_16x16x32_bf16(af[mt], bf[nt], acc[mt][nt], 0, 0, 0);
        }
        __builtin_amdgcn_s_setprio(0);
        __builtin_amdgcn_sched_barrier(0);
        __builtin_amdgcn_s_barrier();                   // all readers done
        __builtin_amdgcn_sched_barrier(0);
        if (kbi < 14) stage(cur, (kbi + 2) * 64);       // refill (overwrite safe)
    }

    // RoPE epilogue
#pragma unroll
    for (int nt = 0; nt < 3; nt++) {
        const int cg = n0 + wn + nt * 16 + l16;      // global col 0..3071
        const int buf = cg >> 10;                    // 0=q 1=k 2=v
        const int c = cg & 1023;
        u16* dst = (buf == 0) ? Yq : ((buf == 1) ? Yk : Yv);
        const bool rp = (buf < 2);
        const float scl = (buf == 0) ? QSCL : 1.0f;
        const int fi = (cg & 63) >> 1;               // pair index in head
#pragma unroll
        for (int mt = 0; mt < 8; mt++)
#pragma unroll
            for (int r = 0; r < 4; r++) {
                const int row = m0 + wm + mt * 16 + quad * 4 + r;
                float v = acc[mt][nt][r];
                if (rp) {
                    const float2 t = tab[((row & 2047) << 5) + fi];
                    const float partner = __shfl_xor(v, 1);
                    v = (l16 & 1) ? fmaf(v, t.x,  partner * t.y)
                                  : fmaf(v, t.x, -partner * t.y);
                }
                dst[(size_t)row * 1024 + c] = f2b(v * scl);
            }
    }
}

// ---------------------------------------------------------------------------
// Out-proj GEMM: 256(m) x 64(n) x 64(k) steps, 512 threads, 8 waves
// (4m x 2n), acc[4][2], dbuf LDS (80KB). Counted-vmcnt (L=5).
// Grid 256 = 1 block/CU. f32 output.
// ---------------------------------------------------------------------------
__global__ __launch_bounds__(512) void gemm_proj(
    const u16* __restrict__ X, const u16* __restrict__ Wb,
    float* __restrict__ Yf)
{
    __shared__ u16 As[2][256 * 64];   // 2 x 32KB
    __shared__ u16 Bs[2][64 * 64];    // 2 x 8KB

    const int tid  = threadIdx.x;
    const int wave = tid >> 6;                          // 0..7
    const int lane = tid & 63;
    const int quad = lane >> 4;
    const int l16  = lane & 15;
    const int wm = (wave >> 1) * 64;                    // 0,64,128,192
    const int wn = (wave & 1) * 32;                     // 0,32
    const int g = blockIdx.x;
    const int rr = g >> 3;                              // 0..31
    const int m0 = ((g & 7) * 2 + (rr >> 4)) * 256;     // 16 m-tiles
    const int n0 = (rr & 15) * 64;                      // 16 n-tiles
    const int lrow = lane >> 3;                         // 0..7 within 8-row slab
    const int cg8  = (lane & 7) ^ lrow;                 // swizzled global unit

    float4v acc[4][2];
#pragma unroll
    for (int mt = 0; mt < 4; mt++)
#pragma unroll
        for (int nt = 0; nt < 2; nt++) acc[mt][nt] = (float4v){0.f, 0.f, 0.f, 0.f};

    auto stage = [&](int bsel, int kb) {                // 5 loads/thread
#pragma unroll
        for (int t = 0; t < 4; t++) {                   // A: 32 slabs of 8 rows
            const int I = wave * 4 + t;
            const u16* gp = X + (size_t)(m0 + I * 8 + lrow) * 1024 + kb + cg8 * 8;
            __builtin_amdgcn_global_load_lds((GV*)gp, (LV*)&As[bsel][I * 512], 16, 0, 0);
        }
        {                                               // B: 8 slabs, 1/wave
            const u16* gp = Wb + (size_t)(n0 + wave * 8 + lrow) * 1024 + kb + cg8 * 8;
            __builtin_amdgcn_global_load_lds((GV*)gp, (LV*)&Bs[bsel][wave * 512], 16, 0, 0);
        }
    };

    stage(0, 0);
    stage(1, 64);                                       // 10 loads in flight

    for (int kbi = 0; kbi < 16; kbi++) {
        const int cur = kbi & 1;
        if (kbi < 15) { asm volatile("s_waitcnt vmcnt(5)" ::: "memory"); }
        else          { asm volatile("s_waitcnt vmcnt(0)" ::: "memory"); }
        __builtin_amdgcn_sched_barrier(0);
        __builtin_amdgcn_s_barrier();                   // all waves: buf[cur] ready
        __builtin_amdgcn_sched_barrier(0);
        __builtin_amdgcn_s_setprio(1);
#pragma unroll
        for (int ks = 0; ks < 2; ks++) {
            const int su = ((ks * 4 + quad) ^ (l16 & 7)) * 8;   // swizzled unit
            short8 af[4], bf[2];
#pragma unroll
            for (int t = 0; t < 4; t++)
                af[t] = *reinterpret_cast<const short8*>(&As[cur][(wm + t * 16 + l16) * 64 + su]);
#pragma unroll
            for (int t = 0; t < 2; t++)
                bf[t] = *reinterpret_cast<const short8*>(&Bs[cur][(wn + t * 16 + l16) * 64 + su]);
#pragma unroll
            for (int mt = 0; mt < 4; mt++)
#pragma unroll
                for (int nt = 0; nt < 2; nt++)
                    acc[mt][nt] = __builtin_amdgcn_mfma_f32_16x16x32_bf16(af[mt], bf[nt], acc[mt][nt], 0, 0, 0);
        }
        __builtin_amdgcn_s_setprio(0);
        __builtin_amdgcn_sched_barrier(0);
        __builtin_amdgcn_s_barrier();                   // all readers done
        __builtin_amdgcn_sched_barrier(0);
        if (kbi < 14) stage(cur, (kbi + 2) * 64);       // refill (overwrite safe)
    }

#pragma unroll
    for (int nt = 0; nt < 2; nt++) {
        const int col = n0 + wn + nt * 16 + l16;
#pragma unroll
        for (int mt = 0; mt < 4; mt++)
#pragma unroll
            for (int r = 0; r < 4; r++) {
                const int row = m0 + wm + mt * 16 + quad * 4 + r;
                Yf[(size_t)row * 1024 + col] = acc[mt][nt][r];
            }
    }
}

// ---------------------------------------------------------------------------
// Flash causal attention (FROZEN, R19 form): paired q-tiles (qtA, 31-qtA)
// -> 512 equal-work blocks, 256 threads. Unnormalized softmax (q
// pre-scaled 0.125*log2e, p = exp2f(s)). Swapped QK^T: lane holds
// S[q=wave*16+l16][k=nt*16+quad*4+r]. sigma-PV: pa[ks] = packed own words
// (no cross-lane); vf = 2 x b64 at sigma'd k-offsets. Double-buffered Vt,
// ONE barrier/iter. K frags direct from global, prefetched. XCD grouping:
// 16 blocks of one (b,h) per XCD L2. O aliases Q.
// ---------------------------------------------------------------------------
__global__ __launch_bounds__(256, 2) void attn_kernel(
    const u16* Q, const u16* __restrict__ K,
    const u16* __restrict__ V, u16* O)
{
    __shared__ __align__(16) u16 Vt[2][64 * VSTR];   // Vt[b][d][s^((d>>4)<<4)]

    const int tid  = threadIdx.x;
    const int wave = tid >> 6;
    const int lane = tid & 63;
    const int quad = lane >> 4;
    const int l16  = lane & 15;
    const int g = blockIdx.x;
    const int xcd = g & 7, slot = g >> 3;
    const int G = (slot >> 4) * 8 + xcd;    // 0..31 = (b,h) group
    const int qtA = slot & 15;              // 0..15
    const int qtB = 31 - qtA;               // 31..16
    const int b = G & 1, h = G >> 1;
    const size_t base = ((size_t)b * 2048) * 1024 + (size_t)h * 64;

    short8 qfA[2], qfB[2];
    {
        const size_t ra = base + (size_t)(qtA * 64 + wave * 16 + l16) * 1024;
        qfA[0] = *reinterpret_cast<const short8*>(Q + ra + quad * 8);
        qfA[1] = *reinterpret_cast<const short8*>(Q + ra + 32 + quad * 8);
        const size_t rb = base + (size_t)(qtB * 64 + wave * 16 + l16) * 1024;
        qfB[0] = *reinterpret_cast<const short8*>(Q + rb + quad * 8);
        qfB[1] = *reinterpret_cast<const short8*>(Q + rb + 32 + quad * 8);
    }

    float4v oA[4], oB[4];
#pragma unroll
    for (int i = 0; i < 4; i++) { oA[i] = (float4v){0.f,0.f,0.f,0.f}; oB[i] = (float4v){0.f,0.f,0.f,0.f}; }
    float sA = 0.f, sB = 0.f;               // row-sum partial for q = wave*16+l16

    const int srow = tid >> 2;             // 0..63 (coalesced: 4 lanes/row)
    const int cb   = (tid & 3) << 4;       // 0,16,32,48
    const int sxw  = srow ^ cb;            // swizzled s ((d>>4)<<4 == cb)

    const u16* Vp = V + base + (size_t)srow * 1024 + cb;
    const u16* kbase = K + base + (size_t)l16 * 1024 + quad * 8;
    int4 vr0 = *reinterpret_cast<const int4*>(Vp);          // tile 0
    int4 vr1 = *reinterpret_cast<const int4*>(Vp + 8);
    short8 kn[4][2], kc[4][2], vf[4][2];
#pragma unroll
    for (int nt = 0; nt < 4; nt++)                          // K tile 0
#pragma unroll
        for (int ks = 0; ks < 2; ks++)
            kn[nt][ks] = *reinterpret_cast<const short8*>(kbase + (size_t)(nt * 16) * 1024 + ks * 32);

    // prologue: stage tile 0 -> Vt[0]; then vr <- tile 1 (qtB >= 16 always)
    {
        const u16* a = reinterpret_cast<const u16*>(&vr0);
        const u16* c = reinterpret_cast<const u16*>(&vr1);
#pragma unroll
        for (int e = 0; e < 8; e++) Vt[0][(cb + e) * VSTR + sxw] = a[e];
#pragma unroll
        for (int e = 0; e < 8; e++) Vt[0][(cb + 8 + e) * VSTR + sxw] = c[e];
    }
    vr0 = *reinterpret_cast<const int4*>(Vp + 65536);
    vr1 = *reinterpret_cast<const int4*>(Vp + 65536 + 8);

    const int qloc = wave * 16 + l16;      // this lane's q within the 64-tile

    // SWAPPED QK: sacc[nt][r] = S[q=qloc][k = nt*16 + quad*4 + r]
    auto qk = [&](const short8 (&qf)[2], float4v (&sacc)[4]) {
#pragma unroll
        for (int nt = 0; nt < 4; nt++) {
            sacc[nt] = (float4v){0.f, 0.f, 0.f, 0.f};
#pragma unroll
            for (int ks = 0; ks < 2; ks++)
                sacc[nt] = __builtin_amdgcn_mfma_f32_16x16x32_bf16(kc[nt][ks], qf[ks], sacc[nt], 0, 0, 0);
        }
    };
    // softmax + pack; sigma-PV: pa[ks] = (w[2ks][0], w[2ks][1], w[2ks+1][0],
    // w[2ks+1][1]) -- lane-local, zero cross-lane ops.
    auto smx = [&](const float4v (&sacc)[4], float &sr, short8 (&pa)[2], bool diag) {
        unsigned int w[4][2];
#pragma unroll
        for (int nt = 0; nt < 4; nt++) {
            float p[4];
#pragma unroll
            for (int r = 0; r < 4; r++) {
                float sv = sacc[nt][r];                      // log2-domain
                if (diag && (nt * 16 + quad * 4 + r > qloc)) sv = -1e30f;
                p[r] = exp2f(sv);                            // masked -> 0
                sr += p[r];
            }
            asm("v_cvt_pk_bf16_f32 %0, %1, %2" : "=v"(w[nt][0]) : "v"(p[0]), "v"(p[1]));
            asm("v_cvt_pk_bf16_f32 %0, %1, %2" : "=v"(w[nt][1]) : "v"(p[2]), "v"(p[3]));
        }
        union { unsigned int u[4]; short8 s8; } t;
        t.u[0] = w[0][0]; t.u[1] = w[0][1]; t.u[2] = w[1][0]; t.u[3] = w[1][1];
        pa[0] = t.s8;
        t.u[0] = w[2][0]; t.u[1] = w[2][1]; t.u[2] = w[3][0]; t.u[3] = w[3][1];
        pa[1] = t.s8;
    };
    auto pv = [&](const short8 (&pa)[2], float4v (&oc)[4]) {
#pragma unroll
        for (int ks = 0; ks < 2; ks++)
#pragma unroll
            for (int dt = 0; dt < 4; dt++)
                oc[dt] = __builtin_amdgcn_mfma_f32_16x16x32_bf16(pa[ks], vf[dt][ks], oc[dt], 0, 0, 0);
    };

    for (int j = 0; j <= qtB; j++) {
        __syncthreads();   // protects Vt[(j+1)&1]: its iter-(j-1) readers done
        if (j < qtB) {     // stage tile j+1 (in vr) -> Vt[(j+1)&1]
            u16* D = Vt[(j + 1) & 1];
            const u16* a = reinterpret_cast<const u16*>(&vr0);
            const u16* c = reinterpret_cast<const u16*>(&vr1);
#pragma unroll
            for (int e = 0; e < 8; e++) D[(cb + e) * VSTR + sxw] = a[e];
#pragma unroll
            for (int e = 0; e < 8; e++) D[(cb + 8 + e) * VSTR + sxw] = c[e];
        }
#pragma unroll
        for (int nt = 0; nt < 4; nt++)
#pragma unroll
            for (int ks = 0; ks < 2; ks++) kc[nt][ks] = kn[nt][ks];
        if (j < qtB) {     // prefetch: V tile j+2, K tile j+1
            if (j + 2 <= qtB) {
                vr0 = *reinterpret_cast<const int4*>(Vp + (size_t)(j + 2) * 65536);
                vr1 = *reinterpret_cast<const int4*>(Vp + (size_t)(j + 2) * 65536 + 8);
            }
            const u16* kb2 = kbase + (size_t)(j + 1) * 65536;
#pragma unroll
            for (int nt = 0; nt < 4; nt++)
#pragma unroll
                for (int ks = 0; ks < 2; ks++)
                    kn[nt][ks] = *reinterpret_cast<const short8*>(kb2 + (size_t)(nt * 16) * 1024 + ks * 32);
        }
        // vf from Vt[j&1], sigma'd k-order: elem e reads V[k(e)][d],
        // k(e) = ks*32 + (e>>2)*16 + quad*4 + (e&3); phys k ^= (d>>4)<<4.
        {
            const u16* B = Vt[j & 1];
#pragma unroll
            for (int dt = 0; dt < 4; dt++) {
                const int rb = (dt * 16 + l16) * VSTR;
#pragma unroll
                for (int ks = 0; ks < 2; ks++) {
                    const int k1 = (ks * 32 + quad * 4) ^ (dt << 4);
                    const int k2 = (ks * 32 + 16 + quad * 4) ^ (dt << 4);
                    union { struct { uint2 lo, hi; } p; short8 s8; } u;
                    u.p.lo = *reinterpret_cast<const uint2*>(&B[rb + k1]);
                    u.p.hi = *reinterpret_cast<const uint2*>(&B[rb + k2]);
                    vf[dt][ks] = u.s8;
                }
            }
        }

        if (j <= qtA) {    // dual proc
            float4v xA[4], xB[4];
            qk(qfA, xA);
            qk(qfB, xB);
            short8 paA[2], paB[2];
            smx(xA, sA, paA, j == qtA);
            smx(xB, sB, paB, false);     // qtB >= 16 > qtA >= j: never diag
            pv(paA, oA);
            pv(paB, oB);
        } else {           // tail: only B remains
            float4v xB[4];
            qk(qfB, xB);
            short8 paB[2];
            smx(xB, sB, paB, j == qtB);
            pv(paB, oB);
        }
    }

    // epilogue: quad-reduce row sums, redistribute via shfl, normalize, write
    float tA = sA, tB = sB;
    tA += __shfl_xor(tA, 16); tA += __shfl_xor(tA, 32);
    tB += __shfl_xor(tB, 16); tB += __shfl_xor(tB, 32);
#pragma unroll
    for (int r = 0; r < 4; r++) {
        const int rl = quad * 4 + r;                 // q-local of o[.][r]
        const float invA = 1.0f / __shfl(tA, rl);    // lane rl holds q=wave*16+rl
        const float invB = 1.0f / __shfl(tB, rl);
        const size_t rowA = base + (size_t)(qtA * 64 + wave * 16 + rl) * 1024;
        const size_t rowB = base + (size_t)(qtB * 64 + wave * 16 + rl) * 1024;
#pragma unroll
        for (int dt = 0; dt < 4; dt++) {
            O[rowA + dt * 16 + l16] = f2b(oA[dt][r] * invA);
            O[rowB + dt * 16 + l16] = f2b(oB[dt][r] * invB);
        }
    }
}

// ---------------------------------------------------------------------------
extern "C" void kernel_launch(void* const* d_in, const int* in_sizes, int n_in,
                              void* d_out, int out_size, void* d_ws, size_t ws_size,
                              hipStream_t stream) {
    (void)in_sizes; (void)n_in; (void)out_size; (void)ws_size;
    const float* x  = (const float*)d_in[0];
    const float* wq = (const float*)d_in[1];
    const float* wk = (const float*)d_in[2];
    const float* wv = (const float*)d_in[3];
    const float* wo = (const float*)d_in[4];

    const size_t MN = (size_t)4096 * 1024;

    // d_out (16MB): xb (8MB) + wcat (6MB) + rope table (512KB in free tail);
    // all consumed before the final fp32 GEMM overwrites d_out.
    u16* xb   = (u16*)d_out;
    u16* wcat = xb + MN;                    // [3072][1024] = wq|wk|wv rows
    float2* tab = (float2*)(wcat + (size_t)3072 * 1024);
    u16* qbuf = (u16*)d_ws;                 // also attention output
    u16* kbuf = qbuf + MN;
    u16* vbuf = kbuf + MN;
    u16* wob  = vbuf + MN;                  // ws total: 26MB

    cvt_all<<<4352, 256, 0, stream>>>((const float4*)x, (const float4*)wq,
                                      (const float4*)wk, (const float4*)wv,
                                      (const float4*)wo, xb, wcat, wob, tab);
    gemm_qkv<<<256, 512, 0, stream>>>(xb, wcat, qbuf, kbuf, vbuf, tab);
    attn_kernel<<<512, 256, 0, stream>>>(qbuf, kbuf, vbuf, qbuf);
    gemm_proj<<<256, 512, 0, stream>>>(qbuf, wob, (float*)d_out);
}

// Round 15
// 199.892 us; speedup vs baseline: 1.5704x; 1.0677x over previous
//
#include <hip/hip_runtime.h>

// MHA forward, B=2, S=2048, D=1024, H=16, Dk=64, causal, RoPE. fp32 I/O.
// Internal bf16 MFMA 16x16x32, fp32 accum.
// Ledger: attn FROZEN at R19 form (70.6us; 6 rewrites NEUTRAL, 5
// restructures FALSIFIED). GEMMs: R20 WIN dbuf 2-phase (228->217);
// R23 WIN counted-vmcnt + raw barriers + setprio (218->214).
// R26: qkv tile 256x192 -> 128x192, grid 256->512 = 2 blocks/CU (LDS
// 80KB x2 = 160KB exactly; 16 waves/CU = 4/SIMD). Theory: at 1 blk/CU the
// two per-K-step barriers serialize all 8 waves (nothing co-resident to
// cover lgkm/convergence); 2 blocks overlap independently (m114; learn_hip
// m103 912TF @3blk/CU simple vs m230 682TF @1blk/CU 2ph). Parameter-only
// change to the proven R23 schedule: acc[4][3], stage=5 loads -> vmcnt(5).
// proj unchanged (one variable per round).

typedef unsigned short u16;
typedef __attribute__((ext_vector_type(8))) short short8;   // 8 bf16 = 4 VGPRs
typedef __attribute__((ext_vector_type(4))) float float4v;  // MFMA C/D

typedef const __attribute__((address_space(1))) void GV;    // global
typedef __attribute__((address_space(3))) void LV;          // LDS

#define VSTR 72   // attn Vt row stride (u16): 144B rows, 2-way read banks
#define QSCL 0.18033688011112042f   // 0.125 * log2(e)

__device__ __forceinline__ u16 f2b(float f) {
    union { float f; unsigned int i; } t; t.f = f;
    unsigned int r = t.i + 0x7fffu + ((t.i >> 16) & 1u);   // RNE
    return (u16)(r >> 16);
}

// ---------------- fused fp32 -> bf16 converter + RoPE table -----------------
// blocks 0..4095: cvt x/wq/wk/wv/wo. blocks 4096..4351: tab[pos*32+fi].
__global__ __launch_bounds__(256) void cvt_all(
    const float4* __restrict__ x,  const float4* __restrict__ wq,
    const float4* __restrict__ wk, const float4* __restrict__ wv,
    const float4* __restrict__ wo,
    u16* __restrict__ xb, u16* __restrict__ wcat, u16* __restrict__ wob,
    float2* __restrict__ tab)
{
    const int blk = blockIdx.x;
    if (blk >= 4096) {                 // RoPE cos/sin table
        const int i = (blk - 4096) * 256 + threadIdx.x;   // 0..65535
        const int pos = i >> 5, fi = i & 31;
        const float freq = exp2f((float)fi * -0.4152410118609203f);  // -log2(1e4)/32
        float sn, cs; sincosf((float)pos * freq, &sn, &cs);
        tab[i] = make_float2(cs, sn);
        return;
    }
    const int i = blk * 256 + threadIdx.x;
    const float4* s; u16* d; int off;
    if (i < 524288) { s = x; d = xb; off = i; }
    else {
        const int widx = i - 524288;
        const int w = widx >> 17, o = widx & 131071;
        switch (w) {
            case 0:  s = wq; d = wcat;              break;
            case 1:  s = wk; d = wcat + (1 << 20);  break;
            case 2:  s = wv; d = wcat + (2 << 20);  break;
            default: s = wo; d = wob;               break;
        }
        off = o;
    }
    float4 a = s[2 * off], b = s[2 * off + 1];
    u16 t[8] = {f2b(a.x), f2b(a.y), f2b(a.z), f2b(a.w),
                f2b(b.x), f2b(b.y), f2b(b.z), f2b(b.w)};
    reinterpret_cast<int4*>(d)[off] = *reinterpret_cast<int4*>(t);
}

// ---------------------------------------------------------------------------
// QKV GEMM (R26): 128(m) x 192(n) x 64(k) steps, 512 threads, 8 waves
// (2m x 4n), per-wave 64x48 (acc[4][3]). Double-buffered LDS (80KB ->
// 2 blocks/CU). Counted-vmcnt schedule: per K-step vmcnt(5) -> barrier ->
// MFMA (setprio 1) -> barrier -> refill K-step kbi+2. Grid 512 = 32m x 16n,
// XCD-grouped. RoPE epilogue.
// ---------------------------------------------------------------------------
__global__ __launch_bounds__(512) void gemm_qkv(
    const u16* __restrict__ X, const u16* __restrict__ Wb,
    u16* __restrict__ Yq, u16* __restrict__ Yk, u16* __restrict__ Yv,
    const float2* __restrict__ tab)
{
    __shared__ u16 As[2][128 * 64];   // 2 x 16KB
    __shared__ u16 Bs[2][192 * 64];   // 2 x 24KB

    const int tid  = threadIdx.x;
    const int wave = tid >> 6;                          // 0..7
    const int lane = tid & 63;
    const int quad = lane >> 4;
    const int l16  = lane & 15;
    const int wm = (wave >> 2) * 64;                    // 0,64
    const int wn = (wave & 3) * 48;                     // 0,48,96,144
    const int g = blockIdx.x;
    const int rr = g >> 3;                              // 0..63
    const int m0 = ((g & 7) * 4 + (rr >> 4)) * 128;     // 32 m-tiles
    const int n0 = (rr & 15) * 192;                     // 16 n-tiles
    const int lrow = lane >> 3;                         // 0..7 within 8-row slab
    const int cg8  = (lane & 7) ^ lrow;                 // swizzled global unit

    float4v acc[4][3];
#pragma unroll
    for (int mt = 0; mt < 4; mt++)
#pragma unroll
        for (int nt = 0; nt < 3; nt++) acc[mt][nt] = (float4v){0.f, 0.f, 0.f, 0.f};

    auto stage = [&](int bsel, int kb) {                // 5 loads/thread
#pragma unroll
        for (int t = 0; t < 2; t++) {                   // A: 16 slabs of 8 rows
            const int I = wave * 2 + t;
            const u16* gp = X + (size_t)(m0 + I * 8 + lrow) * 1024 + kb + cg8 * 8;
            __builtin_amdgcn_global_load_lds((GV*)gp, (LV*)&As[bsel][I * 512], 16, 0, 0);
        }
#pragma unroll
        for (int t = 0; t < 3; t++) {                   // B: 24 slabs of 8 rows
            const int I = wave * 3 + t;
            const u16* gp = Wb + (size_t)(n0 + I * 8 + lrow) * 1024 + kb + cg8 * 8;
            __builtin_amdgcn_global_load_lds((GV*)gp, (LV*)&Bs[bsel][I * 512], 16, 0, 0);
        }
    };

    stage(0, 0);
    stage(1, 64);                                       // 10 loads in flight

    for (int kbi = 0; kbi < 16; kbi++) {
        const int cur = kbi & 1;
        if (kbi < 15) { asm volatile("s_waitcnt vmcnt(5)" ::: "memory"); }
        else          { asm volatile("s_waitcnt vmcnt(0)" ::: "memory"); }
        __builtin_amdgcn_sched_barrier(0);
        __builtin_amdgcn_s_barrier();                   // all waves: buf[cur] ready
        __builtin_amdgcn_sched_barrier(0);
        __builtin_amdgcn_s_setprio(1);
#pragma unroll
        for (int ks = 0; ks < 2; ks++) {
            const int su = ((ks * 4 + quad) ^ (l16 & 7)) * 8;   // swizzled unit
            short8 af[4], bf[3];
#pragma unroll
            for (int t = 0; t < 4; t++)
                af[t] = *reinterpret_cast<const short8*>(&As[cur][(wm + t * 16 + l16) * 64 + su]);
#pragma unroll
            for (int t = 0; t < 3; t++)
                bf[t] = *reinterpret_cast<const short8*>(&Bs[cur][(wn + t * 16 + l16) * 64 + su]);
#pragma unroll
            for (int mt = 0; mt < 4; mt++)
#pragma unroll
                for (int nt = 0; nt < 3; nt++)
                    acc[mt][nt] = __builtin_amdgcn_mfma_f32_16x16x32_bf16(af[mt], bf[nt], acc[mt][nt], 0, 0, 0);
        }
        __builtin_amdgcn_s_setprio(0);
        __builtin_amdgcn_sched_barrier(0);
        __builtin_amdgcn_s_barrier();                   // all readers done
        __builtin_amdgcn_sched_barrier(0);
        if (kbi < 14) stage(cur, (kbi + 2) * 64);       // refill (overwrite safe)
    }

    // RoPE epilogue
#pragma unroll
    for (int nt = 0; nt < 3; nt++) {
        const int cg = n0 + wn + nt * 16 + l16;      // global col 0..3071
        const int buf = cg >> 10;                    // 0=q 1=k 2=v
        const int c = cg & 1023;
        u16* dst = (buf == 0) ? Yq : ((buf == 1) ? Yk : Yv);
        const bool rp = (buf < 2);
        const float scl = (buf == 0) ? QSCL : 1.0f;
        const int fi = (cg & 63) >> 1;               // pair index in head
#pragma unroll
        for (int mt = 0; mt < 4; mt++)
#pragma unroll
            for (int r = 0; r < 4; r++) {
                const int row = m0 + wm + mt * 16 + quad * 4 + r;
                float v = acc[mt][nt][r];
                if (rp) {
                    const float2 t = tab[((row & 2047) << 5) + fi];
                    const float partner = __shfl_xor(v, 1);
                    v = (l16 & 1) ? fmaf(v, t.x,  partner * t.y)
                                  : fmaf(v, t.x, -partner * t.y);
                }
                dst[(size_t)row * 1024 + c] = f2b(v * scl);
            }
    }
}

// ---------------------------------------------------------------------------
// Out-proj GEMM: 256(m) x 64(n) x 64(k) steps, 512 threads, 8 waves
// (4m x 2n), acc[4][2], dbuf LDS (80KB). Counted-vmcnt (L=5).
// Grid 256 = 1 block/CU. f32 output.
// ---------------------------------------------------------------------------
__global__ __launch_bounds__(512) void gemm_proj(
    const u16* __restrict__ X, const u16* __restrict__ Wb,
    float* __restrict__ Yf)
{
    __shared__ u16 As[2][256 * 64];   // 2 x 32KB
    __shared__ u16 Bs[2][64 * 64];    // 2 x 8KB

    const int tid  = threadIdx.x;
    const int wave = tid >> 6;                          // 0..7
    const int lane = tid & 63;
    const int quad = lane >> 4;
    const int l16  = lane & 15;
    const int wm = (wave >> 1) * 64;                    // 0,64,128,192
    const int wn = (wave & 1) * 32;                     // 0,32
    const int g = blockIdx.x;
    const int rr = g >> 3;                              // 0..31
    const int m0 = ((g & 7) * 2 + (rr >> 4)) * 256;     // 16 m-tiles
    const int n0 = (rr & 15) * 64;                      // 16 n-tiles
    const int lrow = lane >> 3;                         // 0..7 within 8-row slab
    const int cg8  = (lane & 7) ^ lrow;                 // swizzled global unit

    float4v acc[4][2];
#pragma unroll
    for (int mt = 0; mt < 4; mt++)
#pragma unroll
        for (int nt = 0; nt < 2; nt++) acc[mt][nt] = (float4v){0.f, 0.f, 0.f, 0.f};

    auto stage = [&](int bsel, int kb) {                // 5 loads/thread
#pragma unroll
        for (int t = 0; t < 4; t++) {                   // A: 32 slabs of 8 rows
            const int I = wave * 4 + t;
            const u16* gp = X + (size_t)(m0 + I * 8 + lrow) * 1024 + kb + cg8 * 8;
            __builtin_amdgcn_global_load_lds((GV*)gp, (LV*)&As[bsel][I * 512], 16, 0, 0);
        }
        {                                               // B: 8 slabs, 1/wave
            const u16* gp = Wb + (size_t)(n0 + wave * 8 + lrow) * 1024 + kb + cg8 * 8;
            __builtin_amdgcn_global_load_lds((GV*)gp, (LV*)&Bs[bsel][wave * 512], 16, 0, 0);
        }
    };

    stage(0, 0);
    stage(1, 64);                                       // 10 loads in flight

    for (int kbi = 0; kbi < 16; kbi++) {
        const int cur = kbi & 1;
        if (kbi < 15) { asm volatile("s_waitcnt vmcnt(5)" ::: "memory"); }
        else          { asm volatile("s_waitcnt vmcnt(0)" ::: "memory"); }
        __builtin_amdgcn_sched_barrier(0);
        __builtin_amdgcn_s_barrier();                   // all waves: buf[cur] ready
        __builtin_amdgcn_sched_barrier(0);
        __builtin_amdgcn_s_setprio(1);
#pragma unroll
        for (int ks = 0; ks < 2; ks++) {
            const int su = ((ks * 4 + quad) ^ (l16 & 7)) * 8;   // swizzled unit
            short8 af[4], bf[2];
#pragma unroll
            for (int t = 0; t < 4; t++)
                af[t] = *reinterpret_cast<const short8*>(&As[cur][(wm + t * 16 + l16) * 64 + su]);
#pragma unroll
            for (int t = 0; t < 2; t++)
                bf[t] = *reinterpret_cast<const short8*>(&Bs[cur][(wn + t * 16 + l16) * 64 + su]);
#pragma unroll
            for (int mt = 0; mt < 4; mt++)
#pragma unroll
                for (int nt = 0; nt < 2; nt++)
                    acc[mt][nt] = __builtin_amdgcn_mfma_f32_16x16x32_bf16(af[mt], bf[nt], acc[mt][nt], 0, 0, 0);
        }
        __builtin_amdgcn_s_setprio(0);
        __builtin_amdgcn_sched_barrier(0);
        __builtin_amdgcn_s_barrier();                   // all readers done
        __builtin_amdgcn_sched_barrier(0);
        if (kbi < 14) stage(cur, (kbi + 2) * 64);       // refill (overwrite safe)
    }

#pragma unroll
    for (int nt = 0; nt < 2; nt++) {
        const int col = n0 + wn + nt * 16 + l16;
#pragma unroll
        for (int mt = 0; mt < 4; mt++)
#pragma unroll
            for (int r = 0; r < 4; r++) {
                const int row = m0 + wm + mt * 16 + quad * 4 + r;
                Yf[(size_t)row * 1024 + col] = acc[mt][nt][r];
            }
    }
}

// ---------------------------------------------------------------------------
// Flash causal attention (FROZEN, R19 form): paired q-tiles (qtA, 31-qtA)
// -> 512 equal-work blocks, 256 threads. Unnormalized softmax (q
// pre-scaled 0.125*log2e, p = exp2f(s)). Swapped QK^T: lane holds
// S[q=wave*16+l16][k=nt*16+quad*4+r]. sigma-PV: pa[ks] = packed own words
// (no cross-lane); vf = 2 x b64 at sigma'd k-offsets. Double-buffered Vt,
// ONE barrier/iter. K frags direct from global, prefetched. XCD grouping:
// 16 blocks of one (b,h) per XCD L2. O aliases Q.
// ---------------------------------------------------------------------------
__global__ __launch_bounds__(256, 2) void attn_kernel(
    const u16* Q, const u16* __restrict__ K,
    const u16* __restrict__ V, u16* O)
{
    __shared__ __align__(16) u16 Vt[2][64 * VSTR];   // Vt[b][d][s^((d>>4)<<4)]

    const int tid  = threadIdx.x;
    const int wave = tid >> 6;
    const int lane = tid & 63;
    const int quad = lane >> 4;
    const int l16  = lane & 15;
    const int g = blockIdx.x;
    const int xcd = g & 7, slot = g >> 3;
    const int G = (slot >> 4) * 8 + xcd;    // 0..31 = (b,h) group
    const int qtA = slot & 15;              // 0..15
    const int qtB = 31 - qtA;               // 31..16
    const int b = G & 1, h = G >> 1;
    const size_t base = ((size_t)b * 2048) * 1024 + (size_t)h * 64;

    short8 qfA[2], qfB[2];
    {
        const size_t ra = base + (size_t)(qtA * 64 + wave * 16 + l16) * 1024;
        qfA[0] = *reinterpret_cast<const short8*>(Q + ra + quad * 8);
        qfA[1] = *reinterpret_cast<const short8*>(Q + ra + 32 + quad * 8);
        const size_t rb = base + (size_t)(qtB * 64 + wave * 16 + l16) * 1024;
        qfB[0] = *reinterpret_cast<const short8*>(Q + rb + quad * 8);
        qfB[1] = *reinterpret_cast<const short8*>(Q + rb + 32 + quad * 8);
    }

    float4v oA[4], oB[4];
#pragma unroll
    for (int i = 0; i < 4; i++) { oA[i] = (float4v){0.f,0.f,0.f,0.f}; oB[i] = (float4v){0.f,0.f,0.f,0.f}; }
    float sA = 0.f, sB = 0.f;               // row-sum partial for q = wave*16+l16

    const int srow = tid >> 2;             // 0..63 (coalesced: 4 lanes/row)
    const int cb   = (tid & 3) << 4;       // 0,16,32,48
    const int sxw  = srow ^ cb;            // swizzled s ((d>>4)<<4 == cb)

    const u16* Vp = V + base + (size_t)srow * 1024 + cb;
    const u16* kbase = K + base + (size_t)l16 * 1024 + quad * 8;
    int4 vr0 = *reinterpret_cast<const int4*>(Vp);          // tile 0
    int4 vr1 = *reinterpret_cast<const int4*>(Vp + 8);
    short8 kn[4][2], kc[4][2], vf[4][2];
#pragma unroll
    for (int nt = 0; nt < 4; nt++)                          // K tile 0
#pragma unroll
        for (int ks = 0; ks < 2; ks++)
            kn[nt][ks] = *reinterpret_cast<const short8*>(kbase + (size_t)(nt * 16) * 1024 + ks * 32);

    // prologue: stage tile 0 -> Vt[0]; then vr <- tile 1 (qtB >= 16 always)
    {
        const u16* a = reinterpret_cast<const u16*>(&vr0);
        const u16* c = reinterpret_cast<const u16*>(&vr1);
#pragma unroll
        for (int e = 0; e < 8; e++) Vt[0][(cb + e) * VSTR + sxw] = a[e];
#pragma unroll
        for (int e = 0; e < 8; e++) Vt[0][(cb + 8 + e) * VSTR + sxw] = c[e];
    }
    vr0 = *reinterpret_cast<const int4*>(Vp + 65536);
    vr1 = *reinterpret_cast<const int4*>(Vp + 65536 + 8);

    const int qloc = wave * 16 + l16;      // this lane's q within the 64-tile

    // SWAPPED QK: sacc[nt][r] = S[q=qloc][k = nt*16 + quad*4 + r]
    auto qk = [&](const short8 (&qf)[2], float4v (&sacc)[4]) {
#pragma unroll
        for (int nt = 0; nt < 4; nt++) {
            sacc[nt] = (float4v){0.f, 0.f, 0.f, 0.f};
#pragma unroll
            for (int ks = 0; ks < 2; ks++)
                sacc[nt] = __builtin_amdgcn_mfma_f32_16x16x32_bf16(kc[nt][ks], qf[ks], sacc[nt], 0, 0, 0);
        }
    };
    // softmax + pack; sigma-PV: pa[ks] = (w[2ks][0], w[2ks][1], w[2ks+1][0],
    // w[2ks+1][1]) -- lane-local, zero cross-lane ops.
    auto smx = [&](const float4v (&sacc)[4], float &sr, short8 (&pa)[2], bool diag) {
        unsigned int w[4][2];
#pragma unroll
        for (int nt = 0; nt < 4; nt++) {
            float p[4];
#pragma unroll
            for (int r = 0; r < 4; r++) {
                float sv = sacc[nt][r];                      // log2-domain
                if (diag && (nt * 16 + quad * 4 + r > qloc)) sv = -1e30f;
                p[r] = exp2f(sv);                            // masked -> 0
                sr += p[r];
            }
            asm("v_cvt_pk_bf16_f32 %0, %1, %2" : "=v"(w[nt][0]) : "v"(p[0]), "v"(p[1]));
            asm("v_cvt_pk_bf16_f32 %0, %1, %2" : "=v"(w[nt][1]) : "v"(p[2]), "v"(p[3]));
        }
        union { unsigned int u[4]; short8 s8; } t;
        t.u[0] = w[0][0]; t.u[1] = w[0][1]; t.u[2] = w[1][0]; t.u[3] = w[1][1];
        pa[0] = t.s8;
        t.u[0] = w[2][0]; t.u[1] = w[2][1]; t.u[2] = w[3][0]; t.u[3] = w[3][1];
        pa[1] = t.s8;
    };
    auto pv = [&](const short8 (&pa)[2], float4v (&oc)[4]) {
#pragma unroll
        for (int ks = 0; ks < 2; ks++)
#pragma unroll
            for (int dt = 0; dt < 4; dt++)
                oc[dt] = __builtin_amdgcn_mfma_f32_16x16x32_bf16(pa[ks], vf[dt][ks], oc[dt], 0, 0, 0);
    };

    for (int j = 0; j <= qtB; j++) {
        __syncthreads();   // protects Vt[(j+1)&1]: its iter-(j-1) readers done
        if (j < qtB) {     // stage tile j+1 (in vr) -> Vt[(j+1)&1]
            u16* D = Vt[(j + 1) & 1];
            const u16* a = reinterpret_cast<const u16*>(&vr0);
            const u16* c = reinterpret_cast<const u16*>(&vr1);
#pragma unroll
            for (int e = 0; e < 8; e++) D[(cb + e) * VSTR + sxw] = a[e];
#pragma unroll
            for (int e = 0; e < 8; e++) D[(cb + 8 + e) * VSTR + sxw] = c[e];
        }
#pragma unroll
        for (int nt = 0; nt < 4; nt++)
#pragma unroll
            for (int ks = 0; ks < 2; ks++) kc[nt][ks] = kn[nt][ks];
        if (j < qtB) {     // prefetch: V tile j+2, K tile j+1
            if (j + 2 <= qtB) {
                vr0 = *reinterpret_cast<const int4*>(Vp + (size_t)(j + 2) * 65536);
                vr1 = *reinterpret_cast<const int4*>(Vp + (size_t)(j + 2) * 65536 + 8);
            }
            const u16* kb2 = kbase + (size_t)(j + 1) * 65536;
#pragma unroll
            for (int nt = 0; nt < 4; nt++)
#pragma unroll
                for (int ks = 0; ks < 2; ks++)
                    kn[nt][ks] = *reinterpret_cast<const short8*>(kb2 + (size_t)(nt * 16) * 1024 + ks * 32);
        }
        // vf from Vt[j&1], sigma'd k-order: elem e reads V[k(e)][d],
        // k(e) = ks*32 + (e>>2)*16 + quad*4 + (e&3); phys k ^= (d>>4)<<4.
        {
            const u16* B = Vt[j & 1];
#pragma unroll
            for (int dt = 0; dt < 4; dt++) {
                const int rb = (dt * 16 + l16) * VSTR;
#pragma unroll
                for (int ks = 0; ks < 2; ks++) {
                    const int k1 = (ks * 32 + quad * 4) ^ (dt << 4);
                    const int k2 = (ks * 32 + 16 + quad * 4) ^ (dt << 4);
                    union { struct { uint2 lo, hi; } p; short8 s8; } u;
                    u.p.lo = *reinterpret_cast<const uint2*>(&B[rb + k1]);
                    u.p.hi = *reinterpret_cast<const uint2*>(&B[rb + k2]);
                    vf[dt][ks] = u.s8;
                }
            }
        }

        if (j <= qtA) {    // dual proc
            float4v xA[4], xB[4];
            qk(qfA, xA);
            qk(qfB, xB);
            short8 paA[2], paB[2];
            smx(xA, sA, paA, j == qtA);
            smx(xB, sB, paB, false);     // qtB >= 16 > qtA >= j: never diag
            pv(paA, oA);
            pv(paB, oB);
        } else {           // tail: only B remains
            float4v xB[4];
            qk(qfB, xB);
            short8 paB[2];
            smx(xB, sB, paB, j == qtB);
            pv(paB, oB);
        }
    }

    // epilogue: quad-reduce row sums, redistribute via shfl, normalize, write
    float tA = sA, tB = sB;
    tA += __shfl_xor(tA, 16); tA += __shfl_xor(tA, 32);
    tB += __shfl_xor(tB, 16); tB += __shfl_xor(tB, 32);
#pragma unroll
    for (int r = 0; r < 4; r++) {
        const int rl = quad * 4 + r;                 // q-local of o[.][r]
        const float invA = 1.0f / __shfl(tA, rl);    // lane rl holds q=wave*16+rl
        const float invB = 1.0f / __shfl(tB, rl);
        const size_t rowA = base + (size_t)(qtA * 64 + wave * 16 + rl) * 1024;
        const size_t rowB = base + (size_t)(qtB * 64 + wave * 16 + rl) * 1024;
#pragma unroll
        for (int dt = 0; dt < 4; dt++) {
            O[rowA + dt * 16 + l16] = f2b(oA[dt][r] * invA);
            O[rowB + dt * 16 + l16] = f2b(oB[dt][r] * invB);
        }
    }
}

// ---------------------------------------------------------------------------
extern "C" void kernel_launch(void* const* d_in, const int* in_sizes, int n_in,
                              void* d_out, int out_size, void* d_ws, size_t ws_size,
                              hipStream_t stream) {
    (void)in_sizes; (void)n_in; (void)out_size; (void)ws_size;
    const float* x  = (const float*)d_in[0];
    const float* wq = (const float*)d_in[1];
    const float* wk = (const float*)d_in[2];
    const float* wv = (const float*)d_in[3];
    const float* wo = (const float*)d_in[4];

    const size_t MN = (size_t)4096 * 1024;

    // d_out (16MB): xb (8MB) + wcat (6MB) + rope table (512KB in free tail);
    // all consumed before the final fp32 GEMM overwrites d_out.
    u16* xb   = (u16*)d_out;
    u16* wcat = xb + MN;                    // [3072][1024] = wq|wk|wv rows
    float2* tab = (float2*)(wcat + (size_t)3072 * 1024);
    u16* qbuf = (u16*)d_ws;                 // also attention output
    u16* kbuf = qbuf + MN;
    u16* vbuf = kbuf + MN;
    u16* wob  = vbuf + MN;                  // ws total: 26MB

    cvt_all<<<4352, 256, 0, stream>>>((const float4*)x, (const float4*)wq,
                                      (const float4*)wk, (const float4*)wv,
                                      (const float4*)wo, xb, wcat, wob, tab);
    gemm_qkv<<<512, 512, 0, stream>>>(xb, wcat, qbuf, kbuf, vbuf, tab);
    attn_kernel<<<512, 256, 0, stream>>>(qbuf, kbuf, vbuf, qbuf);
    gemm_proj<<<256, 512, 0, stream>>>(qbuf, wob, (float*)d_out);
}